// Round 7
// baseline (261.146 us; speedup 1.0000x reference)
//
#include <hip/hip_runtime.h>
#include <cmath>

#define ROWS 4096      // B*N
#define DIM 768        // D
#define QKV_COLS 2304  // 3*D
#define NHEAD 12
#define HEAD_DIM 64
#define SEQ 2048
#define PADK 72        // LDS row stride (bf16) for VALU-written tiles (Ps, transpose scratch)

static constexpr float SCALE_F = 0.125f;   // HD^-0.5
static constexpr float EPS_F   = 1e-8f;

typedef __bf16 bfrag __attribute__((ext_vector_type(8)));   // 8 bf16 = 4 VGPR (MFMA A/B frag)
typedef float  f32x4 __attribute__((ext_vector_type(4)));   // MFMA C/D frag

__device__ __forceinline__ float wave_sum64(float v) {
#pragma unroll
  for (int off = 1; off < 64; off <<= 1) v += __shfl_xor(v, off, 64);
  return v;
}

__device__ __forceinline__ unsigned short f2bf(float f) {
  unsigned u = __float_as_uint(f);
  u += 0x7fffu + ((u >> 16) & 1u);
  return (unsigned short)(u >> 16);
}

__device__ __forceinline__ void gl_lds16(const void* g, void* l) {
  __builtin_amdgcn_global_load_lds((const __attribute__((address_space(1))) void*)g,
                                   (__attribute__((address_space(3))) void*)l, 16, 0, 0);
}

// ---------------- f32 -> bf16 cast (both weight tensors, one launch) ----------------
__global__ __launch_bounds__(256) void conv_bf16_2(const float* __restrict__ a, int na,
                                                   const float* __restrict__ b, int nb,
                                                   unsigned short* __restrict__ da,
                                                   unsigned short* __restrict__ db) {
  const int i = (blockIdx.x * 256 + threadIdx.x) * 4;
  const float* s;
  unsigned short* d;
  int j;
  if (i < na) { s = a; d = da; j = i; }
  else { j = i - na; if (j >= nb) return; s = b; d = db; }
  const float4 v = *(const float4*)(s + j);
  ushort4 o;
  o.x = f2bf(v.x); o.y = f2bf(v.y); o.z = f2bf(v.z); o.w = f2bf(v.w);
  *(ushort4*)(d + j) = o;
}

// ---------------- log0 -> bf16 tangent vectors ----------------
__global__ __launch_bounds__(256) void log0_kernel(const float* __restrict__ x,
                                                   const float* __restrict__ cptr,
                                                   unsigned short* __restrict__ vout) {
  const int lane = threadIdx.x & 63;
  const int row  = (blockIdx.x << 2) + (threadIdx.x >> 6);
  const float* xr = x + (size_t)row * DIM;
  unsigned short* vr = vout + (size_t)row * DIM;
  float vals[12];
  float ss = 0.f;
#pragma unroll
  for (int i = 0; i < 12; ++i) {
    float t = xr[lane + (i << 6)];
    vals[i] = t;
    ss += t * t;
  }
  ss = wave_sum64(ss);
  const float sc  = sqrtf(cptr[0]);
  const float n   = fmaxf(sqrtf(ss), EPS_F);
  const float scn = sc * n;
  const float t   = fminf(scn, 1.0f - 1e-7f);
  const float f   = atanhf(t) / scn;
#pragma unroll
  for (int i = 0; i < 12; ++i) vr[lane + (i << 6)] = f2bf(vals[i] * f);
}

// ---------------- final exp0: out = tanh(sc*n) * v / (sc*n) ----------------
__global__ __launch_bounds__(256) void exp0_out_kernel(const float* __restrict__ vin,
                                                       const float* __restrict__ cptr,
                                                       float* __restrict__ outp) {
  const int lane = threadIdx.x & 63;
  const int row  = (blockIdx.x << 2) + (threadIdx.x >> 6);
  const float* vr = vin + (size_t)row * DIM;
  float* orow = outp + (size_t)row * DIM;
  float vals[12];
  float ss = 0.f;
#pragma unroll
  for (int i = 0; i < 12; ++i) {
    float t = vr[lane + (i << 6)];
    vals[i] = t;
    ss += t * t;
  }
  ss = wave_sum64(ss);
  const float sc  = sqrtf(cptr[0]);
  const float n   = fmaxf(sqrtf(ss), EPS_F);
  const float scn = sc * n;
  const float f   = tanhf(scn) / scn;
#pragma unroll
  for (int i = 0; i < 12; ++i) orow[lane + (i << 6)] = vals[i] * f;
}

// ---------------- MFMA GEMM NT, prefetch double-buffered ----------------
template<int BM, int BN>
__global__ __launch_bounds__(256) void gemm_nt_dbuf(const unsigned short* __restrict__ A,
                                                    const unsigned short* __restrict__ B,
                                                    float* __restrict__ C,
                                                    int M, int Ncols, int K,
                                                    const float* __restrict__ bias) {
  constexpr int FI = BM / 32;
  constexpr int FJ = BN / 32;
  constexpr int CH = BM / 64;
  __shared__ unsigned short As[2][BM * 32];
  __shared__ unsigned short Bs[2][BN * 32];
  const int tid = threadIdx.x;
  const int w = tid >> 6, lane = tid & 63;
  const int lq = lane & 15, quad = lane >> 4;
  const int wr = w >> 1, wc = w & 1;
  const int row0 = blockIdx.y * BM;
  const int col0 = blockIdx.x * BN;
  const int srow  = lane >> 2;
  const int skoff = (lane & 3) << 3;

  f32x4 acc[FI][FJ];
#pragma unroll
  for (int i = 0; i < FI; ++i)
#pragma unroll
    for (int j = 0; j < FJ; ++j) acc[i][j] = (f32x4){0.f, 0.f, 0.f, 0.f};

  auto pf = [&](int k0, int buf) {
#pragma unroll
    for (int c = 0; c < CH; ++c) {
      const int r = c * 64 + w * 16;
      gl_lds16(A + (size_t)(row0 + r + srow) * K + k0 + skoff, &As[buf][r * 32]);
      gl_lds16(B + (size_t)(col0 + r + srow) * K + k0 + skoff, &Bs[buf][r * 32]);
    }
  };

  pf(0, 0);
  const int NIT = K / 32;
  for (int it = 0; it < NIT; ++it) {
    const int buf = it & 1;
    __syncthreads();
    if (it + 1 < NIT) pf((it + 1) * 32, buf ^ 1);

    bfrag af[FI], bfg[FJ];
#pragma unroll
    for (int i = 0; i < FI; ++i)
      af[i] = *(const bfrag*)&As[buf][(wr * (BM / 2) + i * 16 + lq) * 32 + (quad << 3)];
#pragma unroll
    for (int j = 0; j < FJ; ++j)
      bfg[j] = *(const bfrag*)&Bs[buf][(wc * (BN / 2) + j * 16 + lq) * 32 + (quad << 3)];
#pragma unroll
    for (int i = 0; i < FI; ++i)
#pragma unroll
      for (int j = 0; j < FJ; ++j)
        acc[i][j] = __builtin_amdgcn_mfma_f32_16x16x32_bf16(af[i], bfg[j], acc[i][j], 0, 0, 0);
  }

#pragma unroll
  for (int i = 0; i < FI; ++i) {
    const int crow = row0 + wr * (BM / 2) + i * 16 + (quad << 2);
#pragma unroll
    for (int j = 0; j < FJ; ++j) {
      const int col = col0 + wc * (BN / 2) + j * 16 + lq;
      const float bj = bias ? bias[col] : 0.0f;
      float* cp = C + (size_t)crow * Ncols + col;
#pragma unroll
      for (int r = 0; r < 4; ++r)
        cp[(size_t)r * Ncols] = acc[i][j][r] + bj;
    }
  }
}

// ------------- fused prep: exp0(q,k) -> bf16 head-major + norms; V -> bf16 transposed ----
__global__ __launch_bounds__(256) void qkv_prep(const float* __restrict__ qkv,
                                                const float* __restrict__ cptr,
                                                unsigned short* __restrict__ qh,
                                                unsigned short* __restrict__ kh,
                                                unsigned short* __restrict__ vth,
                                                float2* __restrict__ qn2,
                                                float2* __restrict__ kn2) {
  const int qt = blockIdx.x, h = blockIdx.y, b = blockIdx.z;
  const int bh = b * NHEAD + h;
  const int tid = threadIdx.x;
  const int w = tid >> 6, lane = tid & 63;
  const float sc = sqrtf(cptr[0]);

  for (int t = 0; t < 32; ++t) {
    const int vv = w * 32 + t;
    const int which = vv & 1;
    const int r = vv >> 1;
    const int n = qt * 64 + r;
    const float v = qkv[((size_t)(b * SEQ + n)) * QKV_COLS + which * DIM + h * HEAD_DIM + lane];
    const float ss = wave_sum64(v * v);
    const float nn = fmaxf(sqrtf(ss), EPS_F);
    const float scn = sc * nn;
    const float f = tanhf(scn) / scn;
    (which ? kh : qh)[((size_t)bh * SEQ + n) * HEAD_DIM + lane] = f2bf(v * f);
    if (lane == 0) {
      const float nrm = ss * f * f;
      (which ? kn2 : qn2)[(size_t)bh * SEQ + n] =
          make_float2(nrm, 1.0f / (1.0f - fminf(nrm, 0.99f)));
    }
  }

  __shared__ unsigned short T[64 * PADK];
  const int r2 = tid >> 2;
  const int c0 = (tid & 3) << 4;
  const float* src = qkv + ((size_t)(b * SEQ + qt * 64 + r2)) * QKV_COLS + 2 * DIM + h * HEAD_DIM + c0;
#pragma unroll
  for (int z = 0; z < 16; z += 4) {
    const float4 v = *(const float4*)(src + z);
    T[(c0 + z + 0) * PADK + r2] = f2bf(v.x);
    T[(c0 + z + 1) * PADK + r2] = f2bf(v.y);
    T[(c0 + z + 2) * PADK + r2] = f2bf(v.z);
    T[(c0 + z + 3) * PADK + r2] = f2bf(v.w);
  }
  __syncthreads();
  const int d  = tid >> 2;
  const int k0 = (tid & 3) << 4;
  unsigned short* dst = vth + ((size_t)bh * HEAD_DIM + d) * SEQ + (size_t)qt * 64 + k0;
  *(uint4*)dst       = *(const uint4*)&T[d * PADK + k0];
  *(uint4*)(dst + 8) = *(const uint4*)&T[d * PADK + k0 + 8];
}

// ------------- MFMA flash attention: barrier-free, direct-global fragments -------------
// 128 threads = 2 waves; each wave owns 32 queries (2 strips of 16). Grid 768 (flat),
// decoded flat%24=bh so all 32 blocks of one head share an XCD's L2 (K/V L2-hot).
// K/V/kn fragments load global->VGPR (no staging LDS, no __syncthreads); only the
// P C->A layout round-trip uses LDS (intra-wave, in-order DS). l computed by MFMA
// with a ones B-fragment (lands row-aligned with oacc). s C-init = -0.5(qn+kn).
__global__ __launch_bounds__(128) void flash_mfma(const unsigned short* __restrict__ qh,
                                                  const unsigned short* __restrict__ kh,
                                                  const unsigned short* __restrict__ vth,
                                                  const float2* __restrict__ qn2,
                                                  const float2* __restrict__ kn2,
                                                  unsigned short* __restrict__ attn_out) {
  const int flat = blockIdx.x;
  const int bhid = flat % 24;     // same-bh blocks land on one XCD (id % 8 const)
  const int qt   = flat / 24;
  const int h = bhid % NHEAD, b = bhid / NHEAD;
  const int bh = b * NHEAD + h;
  const int tid = threadIdx.x;
  const int w = tid >> 6, lane = tid & 63;
  const int lq = lane & 15, quad = lane >> 4;

  __shared__ unsigned short Ps[64 * PADK];   // [q][key], stride 72; per-wave 32-row halves

  const unsigned short* khb = kh  + (size_t)bh * SEQ * HEAD_DIM;
  const unsigned short* vtb = vth + (size_t)bh * HEAD_DIM * SEQ;
  const float2* knb = kn2 + (size_t)bh * SEQ;
  const unsigned short* qbase = qh + ((size_t)bh * SEQ + (size_t)qt * 64 + w * 32) * HEAD_DIM;
  const float2* qnb = qn2 + (size_t)bh * SEQ + (size_t)qt * 64 + w * 32;

  // Q fragments (B operand in S^T): frag[l][j] = Q[q=strip*16+(l&15)][khf*32+quad*8+j]
  bfrag aq[2][2];
#pragma unroll
  for (int sp = 0; sp < 2; ++sp)
#pragma unroll
    for (int khf = 0; khf < 2; ++khf)
      aq[sp][khf] = *(const bfrag*)(qbase + (size_t)(sp * 16 + lq) * HEAD_DIM + khf * 32 + quad * 8);

  float qn_h[2], qm2[2];
#pragma unroll
  for (int sp = 0; sp < 2; ++sp) {
    const float2 qq = qnb[sp * 16 + lq];
    qn_h[sp] = -0.5f * qq.x;     // C-init contribution
    qm2[sp]  = -4.0f * qq.y;     // -2 * (2/(1-qc)); inner = fma(min(s,0), qm2*rc_k, 1)
  }

  bfrag ones;
#pragma unroll
  for (int j = 0; j < 8; ++j) ones[j] = (__bf16)1.0f;

  f32x4 oacc[2][4];
  f32x4 lacc[2];
#pragma unroll
  for (int sp = 0; sp < 2; ++sp) {
    lacc[sp] = (f32x4){0.f, 0.f, 0.f, 0.f};
#pragma unroll
    for (int d = 0; d < 4; ++d) oacc[sp][d] = (f32x4){0.f, 0.f, 0.f, 0.f};
  }

  for (int kt = 0; kt < SEQ / 64; ++kt) {
    const int key0 = kt * 64;

    // kn pairs for this lane's 16 keys (addresses uniform across lq -> broadcast loads)
    f32x4 kv0[4], kv1[4];
#pragma unroll
    for (int st = 0; st < 4; ++st) {
      const float* kp = (const float*)(knb + key0 + st * 16 + quad * 4);
      kv0[st] = *(const f32x4*)kp;
      kv1[st] = *(const f32x4*)(kp + 4);
    }

    // K fragments direct from global: A[m=key=st*16+lq][k=khf*32+quad*8+j]
    bfrag ak[4][2];
#pragma unroll
    for (int st = 0; st < 4; ++st)
#pragma unroll
      for (int khf = 0; khf < 2; ++khf)
        ak[st][khf] = *(const bfrag*)(khb + (size_t)(key0 + st * 16 + lq) * HEAD_DIM + khf * 32 + quad * 8);

    // ---- S^T = K.Q^T + C-init(-0.5(qn+kn)) ----
    f32x4 s[2][4];
#pragma unroll
    for (int sp = 0; sp < 2; ++sp)
#pragma unroll
      for (int st = 0; st < 4; ++st)
        s[sp][st] = (f32x4){fmaf(kv0[st][0], -0.5f, qn_h[sp]),
                            fmaf(kv0[st][2], -0.5f, qn_h[sp]),
                            fmaf(kv1[st][0], -0.5f, qn_h[sp]),
                            fmaf(kv1[st][2], -0.5f, qn_h[sp])};
#pragma unroll
    for (int khf = 0; khf < 2; ++khf)
#pragma unroll
      for (int sp = 0; sp < 2; ++sp)
#pragma unroll
        for (int st = 0; st < 4; ++st)
          s[sp][st] = __builtin_amdgcn_mfma_f32_16x16x32_bf16(ak[st][khf], aq[sp][khf], s[sp][st], 0, 0, 0);

    // V fragments direct from global: B[k=key0+khf*32+quad*8+j][n=d*16+lq]
    bfrag bv[2][4];
#pragma unroll
    for (int khf = 0; khf < 2; ++khf)
#pragma unroll
      for (int d = 0; d < 4; ++d)
        bv[khf][d] = *(const bfrag*)(vtb + (size_t)(d * 16 + lq) * SEQ + key0 + khf * 32 + quad * 8);

    // ---- w = (inner + sqrt(inner^2-1))^(-1/8), packed to bf16 Ps ----
#pragma unroll
    for (int sp = 0; sp < 2; ++sp)
#pragma unroll
      for (int st = 0; st < 4; ++st) {
        const float rc[4] = {kv0[st][1], kv0[st][3], kv1[st][1], kv1[st][3]};
        unsigned u[4];
#pragma unroll
        for (int i = 0; i < 4; ++i) {
          const float sm = fminf(s[sp][st][i], 0.0f);
          const float inner = fmaf(sm, qm2[sp] * rc[i], 1.0f);
          const float root = __builtin_amdgcn_sqrtf(fmaf(inner, inner, -1.0f));
          const float wgt = __builtin_amdgcn_exp2f(-0.125f * __builtin_amdgcn_logf(inner + root));
          u[i] = __float_as_uint(wgt);
        }
        uint2 pk;
        pk.x = __builtin_amdgcn_perm(u[1], u[0], 0x07060302u);
        pk.y = __builtin_amdgcn_perm(u[3], u[2], 0x07060302u);
        *(uint2*)&Ps[(w * 32 + sp * 16 + lq) * PADK + st * 16 + quad * 4] = pk;
      }

    // ---- O += P.V ; l += P.1 (intra-wave Ps, DS in-order: no barrier) ----
#pragma unroll
    for (int khf = 0; khf < 2; ++khf)
#pragma unroll
      for (int sp = 0; sp < 2; ++sp) {
        const bfrag ap = *(const bfrag*)&Ps[(w * 32 + sp * 16 + lq) * PADK + khf * 32 + quad * 8];
        lacc[sp] = __builtin_amdgcn_mfma_f32_16x16x32_bf16(ap, ones, lacc[sp], 0, 0, 0);
#pragma unroll
        for (int d = 0; d < 4; ++d)
          oacc[sp][d] = __builtin_amdgcn_mfma_f32_16x16x32_bf16(ap, bv[khf][d], oacc[sp][d], 0, 0, 0);
      }
  }

  // lacc C-layout row = q = quad*4+i (all cols equal) -- already aligned with oacc rows
#pragma unroll
  for (int sp = 0; sp < 2; ++sp) {
    float rl4[4];
#pragma unroll
    for (int i = 0; i < 4; ++i) rl4[i] = __builtin_amdgcn_rcpf(lacc[sp][i]);
    unsigned short* ob = attn_out +
        ((size_t)b * SEQ + (size_t)qt * 64 + w * 32 + sp * 16) * DIM + h * HEAD_DIM;
#pragma unroll
    for (int d = 0; d < 4; ++d)
#pragma unroll
      for (int i = 0; i < 4; ++i)
        ob[(size_t)(quad * 4 + i) * DIM + d * 16 + lq] = f2bf(oacc[sp][d][i] * rl4[i]);
  }
}

extern "C" void kernel_launch(void* const* d_in, const int* in_sizes, int n_in,
                              void* d_out, int out_size, void* d_ws, size_t ws_size,
                              hipStream_t stream) {
  const float* x      = (const float*)d_in[0];
  const float* w_qkv  = (const float*)d_in[1];
  const float* w_proj = (const float*)d_in[2];
  const float* b_proj = (const float*)d_in[3];
  const float* curv   = (const float*)d_in[4];
  float* outp = (float*)d_out;

  float* ws = (float*)d_ws;
  unsigned short* v_tan_bf = (unsigned short*)ws;
  unsigned short* attn_bf  = (unsigned short*)ws;
  float* qkv   = ws + 1572864;
  float* v_out = qkv;
  unsigned short* qh  = (unsigned short*)(qkv + 9437184);
  unsigned short* kh  = qh + 3145728;
  unsigned short* vth = kh + 3145728;
  unsigned short* wqkv_bf  = vth + 3145728;
  unsigned short* wproj_bf = wqkv_bf + 1769472;
  float2* qn2 = (float2*)(wproj_bf + 589824);
  float2* kn2 = qn2 + 49152;

  conv_bf16_2<<<dim3((2359296 / 4 + 255) / 256), dim3(256), 0, stream>>>(
      w_qkv, 1769472, w_proj, 589824, wqkv_bf, wproj_bf);
  log0_kernel<<<dim3(ROWS / 4), dim3(256), 0, stream>>>(x, curv, v_tan_bf);
  gemm_nt_dbuf<128, 128><<<dim3(QKV_COLS / 128, ROWS / 128), dim3(256), 0, stream>>>(
      v_tan_bf, wqkv_bf, qkv, ROWS, QKV_COLS, DIM, nullptr);
  qkv_prep<<<dim3(SEQ / 64, NHEAD, 2), dim3(256), 0, stream>>>(qkv, curv, qh, kh, vth,
                                                               qn2, kn2);
  flash_mfma<<<dim3(768), dim3(128), 0, stream>>>(qh, kh, vth, qn2, kn2, attn_bf);
  gemm_nt_dbuf<64, 64><<<dim3(DIM / 64, ROWS / 64), dim3(256), 0, stream>>>(
      attn_bf, wproj_bf, v_out, ROWS, DIM, DIM, b_proj);
  exp0_out_kernel<<<dim3(ROWS / 4), dim3(256), 0, stream>>>(v_out, curv, outp);
}

// Round 8
// 256.645 us; speedup vs baseline: 1.0175x; 1.0175x over previous
//
#include <hip/hip_runtime.h>
#include <cmath>

#define ROWS 4096      // B*N
#define DIM 768        // D
#define QKV_COLS 2304  // 3*D
#define NHEAD 12
#define HEAD_DIM 64
#define SEQ 2048
#define PADK 72        // LDS row stride (bf16) for VALU-written tiles (Ps, transpose scratch)

static constexpr float SCALE_F = 0.125f;   // HD^-0.5
static constexpr float EPS_F   = 1e-8f;

typedef __bf16 bfrag __attribute__((ext_vector_type(8)));   // 8 bf16 = 4 VGPR (MFMA A/B frag)
typedef float  f32x4 __attribute__((ext_vector_type(4)));   // MFMA C/D frag

__device__ __forceinline__ float wave_sum64(float v) {
#pragma unroll
  for (int off = 1; off < 64; off <<= 1) v += __shfl_xor(v, off, 64);
  return v;
}

__device__ __forceinline__ unsigned short f2bf(float f) {
  unsigned u = __float_as_uint(f);
  u += 0x7fffu + ((u >> 16) & 1u);
  return (unsigned short)(u >> 16);
}

__device__ __forceinline__ void gl_lds16(const void* g, void* l) {
  __builtin_amdgcn_global_load_lds((const __attribute__((address_space(1))) void*)g,
                                   (__attribute__((address_space(3))) void*)l, 16, 0, 0);
}

// ---------------- f32 -> bf16 cast (both weight tensors, one launch) ----------------
__global__ __launch_bounds__(256) void conv_bf16_2(const float* __restrict__ a, int na,
                                                   const float* __restrict__ b, int nb,
                                                   unsigned short* __restrict__ da,
                                                   unsigned short* __restrict__ db) {
  const int i = (blockIdx.x * 256 + threadIdx.x) * 4;
  const float* s;
  unsigned short* d;
  int j;
  if (i < na) { s = a; d = da; j = i; }
  else { j = i - na; if (j >= nb) return; s = b; d = db; }
  const float4 v = *(const float4*)(s + j);
  ushort4 o;
  o.x = f2bf(v.x); o.y = f2bf(v.y); o.z = f2bf(v.z); o.w = f2bf(v.w);
  *(ushort4*)(d + j) = o;
}

// ---------------- log0 -> bf16 tangent vectors ----------------
__global__ __launch_bounds__(256) void log0_kernel(const float* __restrict__ x,
                                                   const float* __restrict__ cptr,
                                                   unsigned short* __restrict__ vout) {
  const int lane = threadIdx.x & 63;
  const int row  = (blockIdx.x << 2) + (threadIdx.x >> 6);
  const float* xr = x + (size_t)row * DIM;
  unsigned short* vr = vout + (size_t)row * DIM;
  float vals[12];
  float ss = 0.f;
#pragma unroll
  for (int i = 0; i < 12; ++i) {
    float t = xr[lane + (i << 6)];
    vals[i] = t;
    ss += t * t;
  }
  ss = wave_sum64(ss);
  const float sc  = sqrtf(cptr[0]);
  const float n   = fmaxf(sqrtf(ss), EPS_F);
  const float scn = sc * n;
  const float t   = fminf(scn, 1.0f - 1e-7f);
  const float f   = atanhf(t) / scn;
#pragma unroll
  for (int i = 0; i < 12; ++i) vr[lane + (i << 6)] = f2bf(vals[i] * f);
}

// ---------------- final exp0: out = tanh(sc*n) * v / (sc*n) ----------------
__global__ __launch_bounds__(256) void exp0_out_kernel(const float* __restrict__ vin,
                                                       const float* __restrict__ cptr,
                                                       float* __restrict__ outp) {
  const int lane = threadIdx.x & 63;
  const int row  = (blockIdx.x << 2) + (threadIdx.x >> 6);
  const float* vr = vin + (size_t)row * DIM;
  float* orow = outp + (size_t)row * DIM;
  float vals[12];
  float ss = 0.f;
#pragma unroll
  for (int i = 0; i < 12; ++i) {
    float t = vr[lane + (i << 6)];
    vals[i] = t;
    ss += t * t;
  }
  ss = wave_sum64(ss);
  const float sc  = sqrtf(cptr[0]);
  const float n   = fmaxf(sqrtf(ss), EPS_F);
  const float scn = sc * n;
  const float f   = tanhf(scn) / scn;
#pragma unroll
  for (int i = 0; i < 12; ++i) orow[lane + (i << 6)] = vals[i] * f;
}

// ---------------- MFMA GEMM NT, prefetch double-buffered ----------------
template<int BM, int BN>
__global__ __launch_bounds__(256) void gemm_nt_dbuf(const unsigned short* __restrict__ A,
                                                    const unsigned short* __restrict__ B,
                                                    float* __restrict__ C,
                                                    int M, int Ncols, int K,
                                                    const float* __restrict__ bias) {
  constexpr int FI = BM / 32;
  constexpr int FJ = BN / 32;
  constexpr int CH = BM / 64;
  __shared__ unsigned short As[2][BM * 32];
  __shared__ unsigned short Bs[2][BN * 32];
  const int tid = threadIdx.x;
  const int w = tid >> 6, lane = tid & 63;
  const int lq = lane & 15, quad = lane >> 4;
  const int wr = w >> 1, wc = w & 1;
  const int row0 = blockIdx.y * BM;
  const int col0 = blockIdx.x * BN;
  const int srow  = lane >> 2;
  const int skoff = (lane & 3) << 3;

  f32x4 acc[FI][FJ];
#pragma unroll
  for (int i = 0; i < FI; ++i)
#pragma unroll
    for (int j = 0; j < FJ; ++j) acc[i][j] = (f32x4){0.f, 0.f, 0.f, 0.f};

  auto pf = [&](int k0, int buf) {
#pragma unroll
    for (int c = 0; c < CH; ++c) {
      const int r = c * 64 + w * 16;
      gl_lds16(A + (size_t)(row0 + r + srow) * K + k0 + skoff, &As[buf][r * 32]);
      gl_lds16(B + (size_t)(col0 + r + srow) * K + k0 + skoff, &Bs[buf][r * 32]);
    }
  };

  pf(0, 0);
  const int NIT = K / 32;
  for (int it = 0; it < NIT; ++it) {
    const int buf = it & 1;
    __syncthreads();
    if (it + 1 < NIT) pf((it + 1) * 32, buf ^ 1);

    bfrag af[FI], bfg[FJ];
#pragma unroll
    for (int i = 0; i < FI; ++i)
      af[i] = *(const bfrag*)&As[buf][(wr * (BM / 2) + i * 16 + lq) * 32 + (quad << 3)];
#pragma unroll
    for (int j = 0; j < FJ; ++j)
      bfg[j] = *(const bfrag*)&Bs[buf][(wc * (BN / 2) + j * 16 + lq) * 32 + (quad << 3)];
#pragma unroll
    for (int i = 0; i < FI; ++i)
#pragma unroll
      for (int j = 0; j < FJ; ++j)
        acc[i][j] = __builtin_amdgcn_mfma_f32_16x16x32_bf16(af[i], bfg[j], acc[i][j], 0, 0, 0);
  }

#pragma unroll
  for (int i = 0; i < FI; ++i) {
    const int crow = row0 + wr * (BM / 2) + i * 16 + (quad << 2);
#pragma unroll
    for (int j = 0; j < FJ; ++j) {
      const int col = col0 + wc * (BN / 2) + j * 16 + lq;
      const float bj = bias ? bias[col] : 0.0f;
      float* cp = C + (size_t)crow * Ncols + col;
#pragma unroll
      for (int r = 0; r < 4; ++r)
        cp[(size_t)r * Ncols] = acc[i][j][r] + bj;
    }
  }
}

// ------------- fused prep: exp0(q,k) -> bf16 head-major + norms; V -> bf16 transposed ----
__global__ __launch_bounds__(256) void qkv_prep(const float* __restrict__ qkv,
                                                const float* __restrict__ cptr,
                                                unsigned short* __restrict__ qh,
                                                unsigned short* __restrict__ kh,
                                                unsigned short* __restrict__ vth,
                                                float2* __restrict__ qn2,
                                                float2* __restrict__ kn2) {
  const int qt = blockIdx.x, h = blockIdx.y, b = blockIdx.z;
  const int bh = b * NHEAD + h;
  const int tid = threadIdx.x;
  const int w = tid >> 6, lane = tid & 63;
  const float sc = sqrtf(cptr[0]);

  for (int t = 0; t < 32; ++t) {
    const int vv = w * 32 + t;
    const int which = vv & 1;
    const int r = vv >> 1;
    const int n = qt * 64 + r;
    const float v = qkv[((size_t)(b * SEQ + n)) * QKV_COLS + which * DIM + h * HEAD_DIM + lane];
    const float ss = wave_sum64(v * v);
    const float nn = fmaxf(sqrtf(ss), EPS_F);
    const float scn = sc * nn;
    const float f = tanhf(scn) / scn;
    (which ? kh : qh)[((size_t)bh * SEQ + n) * HEAD_DIM + lane] = f2bf(v * f);
    if (lane == 0) {
      const float nrm = ss * f * f;
      (which ? kn2 : qn2)[(size_t)bh * SEQ + n] =
          make_float2(nrm, 1.0f / (1.0f - fminf(nrm, 0.99f)));
    }
  }

  __shared__ unsigned short T[64 * PADK];
  const int r2 = tid >> 2;
  const int c0 = (tid & 3) << 4;
  const float* src = qkv + ((size_t)(b * SEQ + qt * 64 + r2)) * QKV_COLS + 2 * DIM + h * HEAD_DIM + c0;
#pragma unroll
  for (int z = 0; z < 16; z += 4) {
    const float4 v = *(const float4*)(src + z);
    T[(c0 + z + 0) * PADK + r2] = f2bf(v.x);
    T[(c0 + z + 1) * PADK + r2] = f2bf(v.y);
    T[(c0 + z + 2) * PADK + r2] = f2bf(v.z);
    T[(c0 + z + 3) * PADK + r2] = f2bf(v.w);
  }
  __syncthreads();
  const int d  = tid >> 2;
  const int k0 = (tid & 3) << 4;
  unsigned short* dst = vth + ((size_t)bh * HEAD_DIM + d) * SEQ + (size_t)qt * 64 + k0;
  *(uint4*)dst       = *(const uint4*)&T[d * PADK + k0];
  *(uint4*)(dst + 8) = *(const uint4*)&T[d * PADK + k0 + 8];
}

// ------------- MFMA flash attention: direct-global fragments, key-split waves -------------
// 256 threads = 4 waves: wave (qg,kg) owns queries qg*32..+32 and key-rounds kt%2==kg
// (16 rounds each) -> 3072 waves total (12/CU) while keeping 32 q/wave VALU economics.
// K/V/kn fragments load global->VGPR (L2-hot via XCD-clustered flat%24 decode); only Ps
// (P C->A layout round-trip) uses LDS intra-wave. Partial (O,l) over disjoint key sets
// combined via LDS with a single __syncthreads. l via MFMA ones-frag; s C-init=-0.5(qn+kn).
__global__ __launch_bounds__(256) void flash_mfma(const unsigned short* __restrict__ qh,
                                                  const unsigned short* __restrict__ kh,
                                                  const unsigned short* __restrict__ vth,
                                                  const float2* __restrict__ qn2,
                                                  const float2* __restrict__ kn2,
                                                  unsigned short* __restrict__ attn_out) {
  const int flat = blockIdx.x;
  const int bhid = flat % 24;     // same-bh blocks land on one XCD (id % 8 const)
  const int qt   = flat / 24;
  const int h = bhid % NHEAD, b = bhid / NHEAD;
  const int bh = b * NHEAD + h;
  const int tid = threadIdx.x;
  const int w = tid >> 6, lane = tid & 63;
  const int lq = lane & 15, quad = lane >> 4;
  const int qg = w >> 1;          // query group (32 queries)
  const int kg = w & 1;           // key parity

  __shared__ unsigned short Ps[128 * PADK];  // per-wave 32-row strips (intra-wave only)
  __shared__ f32x4 comb[2][64][10];          // cross-wave (O,l) partials: [qg][lane][2sp*(4d+1)]

  const unsigned short* khb = kh  + (size_t)bh * SEQ * HEAD_DIM;
  const unsigned short* vtb = vth + (size_t)bh * HEAD_DIM * SEQ;
  const float2* knb = kn2 + (size_t)bh * SEQ;
  const unsigned short* qbase = qh + ((size_t)bh * SEQ + (size_t)qt * 64 + qg * 32) * HEAD_DIM;
  const float2* qnb = qn2 + (size_t)bh * SEQ + (size_t)qt * 64 + qg * 32;

  // Q fragments (B operand in S^T): frag[l][j] = Q[q=strip*16+(l&15)][khf*32+quad*8+j]
  bfrag aq[2][2];
#pragma unroll
  for (int sp = 0; sp < 2; ++sp)
#pragma unroll
    for (int khf = 0; khf < 2; ++khf)
      aq[sp][khf] = *(const bfrag*)(qbase + (size_t)(sp * 16 + lq) * HEAD_DIM + khf * 32 + quad * 8);

  float qn_h[2], qm2[2];
#pragma unroll
  for (int sp = 0; sp < 2; ++sp) {
    const float2 qq = qnb[sp * 16 + lq];
    qn_h[sp] = -0.5f * qq.x;     // C-init contribution
    qm2[sp]  = -4.0f * qq.y;     // inner = fma(min(s,0), qm2*rc_k, 1)
  }

  bfrag ones;
#pragma unroll
  for (int j = 0; j < 8; ++j) ones[j] = (__bf16)1.0f;

  f32x4 oacc[2][4];
  f32x4 lacc[2];
#pragma unroll
  for (int sp = 0; sp < 2; ++sp) {
    lacc[sp] = (f32x4){0.f, 0.f, 0.f, 0.f};
#pragma unroll
    for (int d = 0; d < 4; ++d) oacc[sp][d] = (f32x4){0.f, 0.f, 0.f, 0.f};
  }

  for (int kt = kg; kt < SEQ / 64; kt += 2) {
    const int key0 = kt * 64;

    // kn pairs for this lane's 16 keys (uniform across lq -> broadcast loads)
    f32x4 kv0[4], kv1[4];
#pragma unroll
    for (int st = 0; st < 4; ++st) {
      const float* kp = (const float*)(knb + key0 + st * 16 + quad * 4);
      kv0[st] = *(const f32x4*)kp;
      kv1[st] = *(const f32x4*)(kp + 4);
    }

    // K fragments direct from global: A[m=key=st*16+lq][k=khf*32+quad*8+j]
    bfrag ak[4][2];
#pragma unroll
    for (int st = 0; st < 4; ++st)
#pragma unroll
      for (int khf = 0; khf < 2; ++khf)
        ak[st][khf] = *(const bfrag*)(khb + (size_t)(key0 + st * 16 + lq) * HEAD_DIM + khf * 32 + quad * 8);

    // ---- S^T = K.Q^T + C-init(-0.5(qn+kn)) ----
    f32x4 s[2][4];
#pragma unroll
    for (int sp = 0; sp < 2; ++sp)
#pragma unroll
      for (int st = 0; st < 4; ++st)
        s[sp][st] = (f32x4){fmaf(kv0[st][0], -0.5f, qn_h[sp]),
                            fmaf(kv0[st][2], -0.5f, qn_h[sp]),
                            fmaf(kv1[st][0], -0.5f, qn_h[sp]),
                            fmaf(kv1[st][2], -0.5f, qn_h[sp])};
#pragma unroll
    for (int khf = 0; khf < 2; ++khf)
#pragma unroll
      for (int sp = 0; sp < 2; ++sp)
#pragma unroll
        for (int st = 0; st < 4; ++st)
          s[sp][st] = __builtin_amdgcn_mfma_f32_16x16x32_bf16(ak[st][khf], aq[sp][khf], s[sp][st], 0, 0, 0);

    // V fragments direct from global: B[k=key0+khf*32+quad*8+j][n=d*16+lq]
    bfrag bv[2][4];
#pragma unroll
    for (int khf = 0; khf < 2; ++khf)
#pragma unroll
      for (int d = 0; d < 4; ++d)
        bv[khf][d] = *(const bfrag*)(vtb + (size_t)(d * 16 + lq) * SEQ + key0 + khf * 32 + quad * 8);

    // ---- w = (inner + sqrt(inner^2-1))^(-1/8), packed to bf16 Ps ----
#pragma unroll
    for (int sp = 0; sp < 2; ++sp)
#pragma unroll
      for (int st = 0; st < 4; ++st) {
        const float rc[4] = {kv0[st][1], kv0[st][3], kv1[st][1], kv1[st][3]};
        unsigned u[4];
#pragma unroll
        for (int i = 0; i < 4; ++i) {
          const float sm = fminf(s[sp][st][i], 0.0f);
          const float inner = fmaf(sm, qm2[sp] * rc[i], 1.0f);
          const float root = __builtin_amdgcn_sqrtf(fmaf(inner, inner, -1.0f));
          const float wgt = __builtin_amdgcn_exp2f(-0.125f * __builtin_amdgcn_logf(inner + root));
          u[i] = __float_as_uint(wgt);
        }
        uint2 pk;
        pk.x = __builtin_amdgcn_perm(u[1], u[0], 0x07060302u);
        pk.y = __builtin_amdgcn_perm(u[3], u[2], 0x07060302u);
        *(uint2*)&Ps[(w * 32 + sp * 16 + lq) * PADK + st * 16 + quad * 4] = pk;
      }

    // ---- O += P.V ; l += P.1 (intra-wave Ps, DS in-order: no barrier) ----
#pragma unroll
    for (int khf = 0; khf < 2; ++khf)
#pragma unroll
      for (int sp = 0; sp < 2; ++sp) {
        const bfrag ap = *(const bfrag*)&Ps[(w * 32 + sp * 16 + lq) * PADK + khf * 32 + quad * 8];
        lacc[sp] = __builtin_amdgcn_mfma_f32_16x16x32_bf16(ap, ones, lacc[sp], 0, 0, 0);
#pragma unroll
        for (int d = 0; d < 4; ++d)
          oacc[sp][d] = __builtin_amdgcn_mfma_f32_16x16x32_bf16(ap, bv[khf][d], oacc[sp][d], 0, 0, 0);
      }
  }

  // ---- combine kg=0/1 partials (disjoint key sets -> plain add), then normalize ----
  if (kg) {
#pragma unroll
    for (int sp = 0; sp < 2; ++sp) {
#pragma unroll
      for (int d = 0; d < 4; ++d) comb[qg][lane][sp * 5 + d] = oacc[sp][d];
      comb[qg][lane][sp * 5 + 4] = lacc[sp];
    }
  }
  __syncthreads();
  if (!kg) {
#pragma unroll
    for (int sp = 0; sp < 2; ++sp) {
      const f32x4 lsum = lacc[sp] + comb[qg][lane][sp * 5 + 4];
      float rl4[4];
#pragma unroll
      for (int i = 0; i < 4; ++i) rl4[i] = __builtin_amdgcn_rcpf(lsum[i]);
      unsigned short* ob = attn_out +
          ((size_t)b * SEQ + (size_t)qt * 64 + qg * 32 + sp * 16) * DIM + h * HEAD_DIM;
#pragma unroll
      for (int d = 0; d < 4; ++d) {
        const f32x4 ot = oacc[sp][d] + comb[qg][lane][sp * 5 + d];
#pragma unroll
        for (int i = 0; i < 4; ++i)
          ob[(size_t)(quad * 4 + i) * DIM + d * 16 + lq] = f2bf(ot[i] * rl4[i]);
      }
    }
  }
}

extern "C" void kernel_launch(void* const* d_in, const int* in_sizes, int n_in,
                              void* d_out, int out_size, void* d_ws, size_t ws_size,
                              hipStream_t stream) {
  const float* x      = (const float*)d_in[0];
  const float* w_qkv  = (const float*)d_in[1];
  const float* w_proj = (const float*)d_in[2];
  const float* b_proj = (const float*)d_in[3];
  const float* curv   = (const float*)d_in[4];
  float* outp = (float*)d_out;

  float* ws = (float*)d_ws;
  unsigned short* v_tan_bf = (unsigned short*)ws;
  unsigned short* attn_bf  = (unsigned short*)ws;
  float* qkv   = ws + 1572864;
  float* v_out = qkv;
  unsigned short* qh  = (unsigned short*)(qkv + 9437184);
  unsigned short* kh  = qh + 3145728;
  unsigned short* vth = kh + 3145728;
  unsigned short* wqkv_bf  = vth + 3145728;
  unsigned short* wproj_bf = wqkv_bf + 1769472;
  float2* qn2 = (float2*)(wproj_bf + 589824);
  float2* kn2 = qn2 + 49152;

  conv_bf16_2<<<dim3((2359296 / 4 + 255) / 256), dim3(256), 0, stream>>>(
      w_qkv, 1769472, w_proj, 589824, wqkv_bf, wproj_bf);
  log0_kernel<<<dim3(ROWS / 4), dim3(256), 0, stream>>>(x, curv, v_tan_bf);
  gemm_nt_dbuf<128, 128><<<dim3(QKV_COLS / 128, ROWS / 128), dim3(256), 0, stream>>>(
      v_tan_bf, wqkv_bf, qkv, ROWS, QKV_COLS, DIM, nullptr);
  qkv_prep<<<dim3(SEQ / 64, NHEAD, 2), dim3(256), 0, stream>>>(qkv, curv, qh, kh, vth,
                                                               qn2, kn2);
  flash_mfma<<<dim3(768), dim3(256), 0, stream>>>(qh, kh, vth, qn2, kn2, attn_bf);
  gemm_nt_dbuf<64, 64><<<dim3(DIM / 64, ROWS / 64), dim3(256), 0, stream>>>(
      attn_bf, wproj_bf, v_out, ROWS, DIM, DIM, b_proj);
  exp0_out_kernel<<<dim3(ROWS / 4), dim3(256), 0, stream>>>(v_out, curv, outp);
}

// Round 9
// 222.828 us; speedup vs baseline: 1.1720x; 1.1518x over previous
//
#include <hip/hip_runtime.h>
#include <cmath>

#define ROWS 4096      // B*N
#define DIM 768        // D
#define QKV_COLS 2304  // 3*D
#define NHEAD 12
#define HEAD_DIM 64
#define SEQ 2048
#define PADK 72        // LDS row stride (bf16) for VALU-written tiles (Ps, transpose scratch)

static constexpr float SCALE_F = 0.125f;   // HD^-0.5
static constexpr float EPS_F   = 1e-8f;

typedef __bf16 bfrag __attribute__((ext_vector_type(8)));   // 8 bf16 = 4 VGPR (MFMA A/B frag)
typedef float  f32x4 __attribute__((ext_vector_type(4)));   // MFMA C/D frag

__device__ __forceinline__ float wave_sum64(float v) {
#pragma unroll
  for (int off = 1; off < 64; off <<= 1) v += __shfl_xor(v, off, 64);
  return v;
}

__device__ __forceinline__ unsigned short f2bf(float f) {
  unsigned u = __float_as_uint(f);
  u += 0x7fffu + ((u >> 16) & 1u);
  return (unsigned short)(u >> 16);
}

// fast tanh(x)/x for x>0:  t=(e-1)/(e+1), e=2^(x*2*log2e);  ->1 as x->0
__device__ __forceinline__ float tanh_over_x(float x) {
  const float e  = __builtin_amdgcn_exp2f(x * 2.8853900817779268f);
  const float th = (e - 1.0f) * __builtin_amdgcn_rcpf(e + 1.0f);
  return (x < 1e-4f) ? 1.0f : th * __builtin_amdgcn_rcpf(x);
}

__device__ __forceinline__ void gl_lds16(const void* g, void* l) {
  __builtin_amdgcn_global_load_lds((const __attribute__((address_space(1))) void*)g,
                                   (__attribute__((address_space(3))) void*)l, 16, 0, 0);
}

// ---------------- f32 -> bf16 cast (both weight tensors, one launch) ----------------
__global__ __launch_bounds__(256) void conv_bf16_2(const float* __restrict__ a, int na,
                                                   const float* __restrict__ b, int nb,
                                                   unsigned short* __restrict__ da,
                                                   unsigned short* __restrict__ db) {
  const int i = (blockIdx.x * 256 + threadIdx.x) * 4;
  const float* s;
  unsigned short* d;
  int j;
  if (i < na) { s = a; d = da; j = i; }
  else { j = i - na; if (j >= nb) return; s = b; d = db; }
  const float4 v = *(const float4*)(s + j);
  ushort4 o;
  o.x = f2bf(v.x); o.y = f2bf(v.y); o.z = f2bf(v.z); o.w = f2bf(v.w);
  *(ushort4*)(d + j) = o;
}

// ---------------- log0 -> bf16 tangent vectors (fast atanh via log2) ----------------
__global__ __launch_bounds__(256) void log0_kernel(const float* __restrict__ x,
                                                   const float* __restrict__ cptr,
                                                   unsigned short* __restrict__ vout) {
  const int lane = threadIdx.x & 63;
  const int row  = (blockIdx.x << 2) + (threadIdx.x >> 6);
  const float* xr = x + (size_t)row * DIM;
  unsigned short* vr = vout + (size_t)row * DIM;
  float vals[12];
  float ss = 0.f;
#pragma unroll
  for (int i = 0; i < 12; ++i) {
    float t = xr[lane + (i << 6)];
    vals[i] = t;
    ss += t * t;
  }
  ss = wave_sum64(ss);
  const float sc  = sqrtf(cptr[0]);
  const float n   = fmaxf(sqrtf(ss), EPS_F);
  const float scn = sc * n;
  const float t   = fminf(scn, 1.0f - 1e-7f);
  // atanh(t) = 0.5*ln((1+t)/(1-t)) = 0.5*ln2 * log2((1+t)/(1-t))
  const float ath = 0.34657359027997264f *
                    __builtin_amdgcn_logf((1.0f + t) * __builtin_amdgcn_rcpf(1.0f - t));
  const float f   = (scn < 1e-4f) ? 1.0f : ath * __builtin_amdgcn_rcpf(scn);
#pragma unroll
  for (int i = 0; i < 12; ++i) vr[lane + (i << 6)] = f2bf(vals[i] * f);
}

// ---------------- final exp0: out = tanh(sc*n) * v / (sc*n) (fast tanh) ----------------
__global__ __launch_bounds__(256) void exp0_out_kernel(const float* __restrict__ vin,
                                                       const float* __restrict__ cptr,
                                                       float* __restrict__ outp) {
  const int lane = threadIdx.x & 63;
  const int row  = (blockIdx.x << 2) + (threadIdx.x >> 6);
  const float* vr = vin + (size_t)row * DIM;
  float* orow = outp + (size_t)row * DIM;
  float vals[12];
  float ss = 0.f;
#pragma unroll
  for (int i = 0; i < 12; ++i) {
    float t = vr[lane + (i << 6)];
    vals[i] = t;
    ss += t * t;
  }
  ss = wave_sum64(ss);
  const float sc  = sqrtf(cptr[0]);
  const float n   = fmaxf(sqrtf(ss), EPS_F);
  const float f   = tanh_over_x(sc * n);
#pragma unroll
  for (int i = 0; i < 12; ++i) orow[lane + (i << 6)] = vals[i] * f;
}

// ---------------- MFMA GEMM NT, prefetch double-buffered ----------------
template<int BM, int BN>
__global__ __launch_bounds__(256) void gemm_nt_dbuf(const unsigned short* __restrict__ A,
                                                    const unsigned short* __restrict__ B,
                                                    float* __restrict__ C,
                                                    int M, int Ncols, int K,
                                                    const float* __restrict__ bias) {
  constexpr int FI = BM / 32;
  constexpr int FJ = BN / 32;
  constexpr int CH = BM / 64;
  __shared__ unsigned short As[2][BM * 32];
  __shared__ unsigned short Bs[2][BN * 32];
  const int tid = threadIdx.x;
  const int w = tid >> 6, lane = tid & 63;
  const int lq = lane & 15, quad = lane >> 4;
  const int wr = w >> 1, wc = w & 1;
  const int row0 = blockIdx.y * BM;
  const int col0 = blockIdx.x * BN;
  const int srow  = lane >> 2;
  const int skoff = (lane & 3) << 3;

  f32x4 acc[FI][FJ];
#pragma unroll
  for (int i = 0; i < FI; ++i)
#pragma unroll
    for (int j = 0; j < FJ; ++j) acc[i][j] = (f32x4){0.f, 0.f, 0.f, 0.f};

  auto pf = [&](int k0, int buf) {
#pragma unroll
    for (int c = 0; c < CH; ++c) {
      const int r = c * 64 + w * 16;
      gl_lds16(A + (size_t)(row0 + r + srow) * K + k0 + skoff, &As[buf][r * 32]);
      gl_lds16(B + (size_t)(col0 + r + srow) * K + k0 + skoff, &Bs[buf][r * 32]);
    }
  };

  pf(0, 0);
  const int NIT = K / 32;
  for (int it = 0; it < NIT; ++it) {
    const int buf = it & 1;
    __syncthreads();
    if (it + 1 < NIT) pf((it + 1) * 32, buf ^ 1);

    bfrag af[FI], bfg[FJ];
#pragma unroll
    for (int i = 0; i < FI; ++i)
      af[i] = *(const bfrag*)&As[buf][(wr * (BM / 2) + i * 16 + lq) * 32 + (quad << 3)];
#pragma unroll
    for (int j = 0; j < FJ; ++j)
      bfg[j] = *(const bfrag*)&Bs[buf][(wc * (BN / 2) + j * 16 + lq) * 32 + (quad << 3)];
#pragma unroll
    for (int i = 0; i < FI; ++i)
#pragma unroll
      for (int j = 0; j < FJ; ++j)
        acc[i][j] = __builtin_amdgcn_mfma_f32_16x16x32_bf16(af[i], bfg[j], acc[i][j], 0, 0, 0);
  }

#pragma unroll
  for (int i = 0; i < FI; ++i) {
    const int crow = row0 + wr * (BM / 2) + i * 16 + (quad << 2);
#pragma unroll
    for (int j = 0; j < FJ; ++j) {
      const int col = col0 + wc * (BN / 2) + j * 16 + lq;
      const float bj = bias ? bias[col] : 0.0f;
      float* cp = C + (size_t)crow * Ncols + col;
#pragma unroll
      for (int r = 0; r < 4; ++r)
        cp[(size_t)r * Ncols] = acc[i][j][r] + bj;
    }
  }
}

// ------------- fused prep: exp0(q,k) -> bf16 head-major + norms; V -> bf16 transposed ----
__global__ __launch_bounds__(256) void qkv_prep(const float* __restrict__ qkv,
                                                const float* __restrict__ cptr,
                                                unsigned short* __restrict__ qh,
                                                unsigned short* __restrict__ kh,
                                                unsigned short* __restrict__ vth,
                                                float2* __restrict__ qn2,
                                                float2* __restrict__ kn2) {
  const int qt = blockIdx.x, h = blockIdx.y, b = blockIdx.z;
  const int bh = b * NHEAD + h;
  const int tid = threadIdx.x;
  const int w = tid >> 6, lane = tid & 63;
  const float sc = sqrtf(cptr[0]);

#pragma unroll 2
  for (int t = 0; t < 32; ++t) {
    const int vv = w * 32 + t;
    const int which = vv & 1;
    const int r = vv >> 1;
    const int n = qt * 64 + r;
    const float v = qkv[((size_t)(b * SEQ + n)) * QKV_COLS + which * DIM + h * HEAD_DIM + lane];
    const float ss = wave_sum64(v * v);
    const float nn = fmaxf(sqrtf(ss), EPS_F);
    const float f  = tanh_over_x(sc * nn);
    (which ? kh : qh)[((size_t)bh * SEQ + n) * HEAD_DIM + lane] = f2bf(v * f);
    if (lane == 0) {
      const float nrm = ss * f * f;
      (which ? kn2 : qn2)[(size_t)bh * SEQ + n] =
          make_float2(nrm, 1.0f / (1.0f - fminf(nrm, 0.99f)));
    }
  }

  __shared__ unsigned short T[64 * PADK];
  const int r2 = tid >> 2;
  const int c0 = (tid & 3) << 4;
  const float* src = qkv + ((size_t)(b * SEQ + qt * 64 + r2)) * QKV_COLS + 2 * DIM + h * HEAD_DIM + c0;
#pragma unroll
  for (int z = 0; z < 16; z += 4) {
    const float4 v = *(const float4*)(src + z);
    T[(c0 + z + 0) * PADK + r2] = f2bf(v.x);
    T[(c0 + z + 1) * PADK + r2] = f2bf(v.y);
    T[(c0 + z + 2) * PADK + r2] = f2bf(v.z);
    T[(c0 + z + 3) * PADK + r2] = f2bf(v.w);
  }
  __syncthreads();
  const int d  = tid >> 2;
  const int k0 = (tid & 3) << 4;
  unsigned short* dst = vth + ((size_t)bh * HEAD_DIM + d) * SEQ + (size_t)qt * 64 + k0;
  *(uint4*)dst       = *(const uint4*)&T[d * PADK + k0];
  *(uint4*)(dst + 8) = *(const uint4*)&T[d * PADK + k0 + 8];
}

// ------------- MFMA flash attention, S^T form, prefetch double-buffered -------------
// block = flat -> (bh = flat%24, qt = flat/24): the 32 blocks of one (b,h) share one XCD's
// L2 (flat%8 constant per bh) so staged K/V reads are L2-hot. 4 waves x 16-query strips;
// 64-key rounds, one barrier each, next round prefetched into the alternate buffer.
// l computed by MFMA vs a ones-fragment -> row-aligned with oacc (no epilogue shuffles).
__global__ __launch_bounds__(256) void flash_mfma(const unsigned short* __restrict__ qh,
                                                  const unsigned short* __restrict__ kh,
                                                  const unsigned short* __restrict__ vth,
                                                  const float2* __restrict__ qn2,
                                                  const float2* __restrict__ kn2,
                                                  unsigned short* __restrict__ attn_out) {
  const int flat = blockIdx.x;
  const int bhid = flat % 24;
  const int qt   = flat / 24;
  const int h = bhid % NHEAD, b = bhid / NHEAD;
  const int bh = b * NHEAD + h;
  const int tid = threadIdx.x;
  const int w = tid >> 6, lane = tid & 63;
  const int lq = lane & 15, quad = lane >> 4;

  __shared__ unsigned short Ks[2][64 * 64];  // swizzled [key][hd]
  __shared__ unsigned short Vt[2][64 * 64];  // swizzled [d][key]
  __shared__ unsigned short Ps[64 * PADK];   // [q][key], stride 72
  __shared__ float knA[2][64], knB[2][64];

  const unsigned short* qbase = qh + ((size_t)bh * SEQ + (size_t)qt * 64) * HEAD_DIM;
  const float2* qnb = qn2 + (size_t)bh * SEQ + (size_t)qt * 64;
  const float2* knb = kn2 + (size_t)bh * SEQ;

  const int srow = tid >> 3, spos = tid & 7;
  const int sB = spos ^ (srow & 7);
  const char* kgsrc = (const char*)(kh + (size_t)bh * SEQ * HEAD_DIM) + (size_t)srow * 128 + sB * 16;
  const char* vgsrc = (const char*)(vth + (size_t)bh * HEAD_DIM * SEQ) + (size_t)srow * 4096 + sB * 16;

  auto prefetch = [&](int kt, int buf) {
    const char* kp = kgsrc + (size_t)kt * 8192;  // 64 keys * 128B
    const char* vp = vgsrc + (size_t)kt * 128;   // 64 keys * 2B per d-row
    gl_lds16(kp,          (char*)Ks[buf] + w * 1024);
    gl_lds16(kp + 4096,   (char*)Ks[buf] + 4096 + w * 1024);
    gl_lds16(vp,          (char*)Vt[buf] + w * 1024);
    gl_lds16(vp + 131072, (char*)Vt[buf] + 4096 + w * 1024);
    if (tid < 64) {
      const float2 kv = knb[kt * 64 + tid];
      knA[buf][tid] = kv.x;
      knB[buf][tid] = kv.y;
    }
  };

  // Q fragments (B operand in S^T): frag[l][j] = Q[q = w*16+(l&15)][hd = khf*32+quad*8+j]
  bfrag aq[2];
#pragma unroll
  for (int khf = 0; khf < 2; ++khf)
    aq[khf] = *(const bfrag*)(qbase + (size_t)(w * 16 + lq) * HEAD_DIM + khf * 32 + quad * 8);

  const float2 qq = qnb[w * 16 + lq];
  const float qnS = qq.x;
  const float rqS = 2.0f * qq.y;

  bfrag ones;
#pragma unroll
  for (int j = 0; j < 8; ++j) ones[j] = (__bf16)1.0f;

  f32x4 oacc[4];
  f32x4 lacc = (f32x4){0.f, 0.f, 0.f, 0.f};
#pragma unroll
  for (int d = 0; d < 4; ++d) oacc[d] = (f32x4){0.f, 0.f, 0.f, 0.f};
  const int swz = lq & 7;

  prefetch(0, 0);
  for (int kt = 0; kt < SEQ / 64; ++kt) {
    const int buf = kt & 1;
    __syncthreads();  // drains prefetch(kt): tiles[buf] ready; all waves done with buf^1
    if (kt + 1 < SEQ / 64) prefetch(kt + 1, buf ^ 1);

    // ---- S^T strip [64k x 16q] = K·Q^T via MFMA ----
    f32x4 s[4];
#pragma unroll
    for (int st = 0; st < 4; ++st) s[st] = (f32x4){0.f, 0.f, 0.f, 0.f};
#pragma unroll
    for (int khf = 0; khf < 2; ++khf)
#pragma unroll
      for (int st = 0; st < 4; ++st) {
        const bfrag ak = *(const bfrag*)&Ks[buf][(st * 16 + lq) * 64 + (((khf << 2) + quad) ^ swz) * 8];
        s[st] = __builtin_amdgcn_mfma_f32_16x16x32_bf16(ak, aq[khf], s[st], 0, 0, 0);
      }

    // ---- w = (inner + sqrt(inner^2-1))^(-1/8); pack 4 keys via v_perm ----
#pragma unroll
    for (int st = 0; st < 4; ++st) {
      const f32x4 kna = *(const f32x4*)&knA[buf][st * 16 + quad * 4];
      const f32x4 knr = *(const f32x4*)&knB[buf][st * 16 + quad * 4];
      unsigned u[4];
#pragma unroll
      for (int i = 0; i < 4; ++i) {
        float tt = fmaf(-2.0f, s[st][i], qnS + kna[i]);
        tt = fmaxf(tt, 0.0f);
        const float inner = fmaf(tt, rqS * knr[i], 1.0f);
        const float root = __builtin_amdgcn_sqrtf(fmaf(inner, inner, -1.0f));
        const float wgt = __builtin_amdgcn_exp2f(-0.125f * __builtin_amdgcn_logf(inner + root));
        u[i] = __float_as_uint(wgt);
      }
      uint2 pk;
      pk.x = __builtin_amdgcn_perm(u[1], u[0], 0x07060302u);
      pk.y = __builtin_amdgcn_perm(u[3], u[2], 0x07060302u);
      *(uint2*)&Ps[(w * 16 + lq) * PADK + st * 16 + quad * 4] = pk;
    }

    // ---- O += P·V ; l += P·1 (intra-wave Ps, DS in-order: no barrier) ----
#pragma unroll
    for (int khf = 0; khf < 2; ++khf) {
      const bfrag ap = *(const bfrag*)&Ps[(w * 16 + lq) * PADK + khf * 32 + quad * 8];
      lacc = __builtin_amdgcn_mfma_f32_16x16x32_bf16(ap, ones, lacc, 0, 0, 0);
#pragma unroll
      for (int d = 0; d < 4; ++d) {
        const bfrag bv = *(const bfrag*)&Vt[buf][(d * 16 + lq) * 64 + (((khf << 2) + quad) ^ swz) * 8];
        oacc[d] = __builtin_amdgcn_mfma_f32_16x16x32_bf16(ap, bv, oacc[d], 0, 0, 0);
      }
    }
  }

  // lacc C-layout: row = q = quad*4+i (all cols equal) — aligned with oacc rows
  float rl4[4];
#pragma unroll
  for (int i = 0; i < 4; ++i) rl4[i] = __builtin_amdgcn_rcpf(lacc[i]);

  unsigned short* ob = attn_out + ((size_t)b * SEQ + (size_t)qt * 64 + w * 16) * DIM + h * HEAD_DIM;
#pragma unroll
  for (int d = 0; d < 4; ++d)
#pragma unroll
    for (int i = 0; i < 4; ++i)
      ob[(size_t)(quad * 4 + i) * DIM + d * 16 + lq] = f2bf(oacc[d][i] * rl4[i]);
}

extern "C" void kernel_launch(void* const* d_in, const int* in_sizes, int n_in,
                              void* d_out, int out_size, void* d_ws, size_t ws_size,
                              hipStream_t stream) {
  const float* x      = (const float*)d_in[0];
  const float* w_qkv  = (const float*)d_in[1];
  const float* w_proj = (const float*)d_in[2];
  const float* b_proj = (const float*)d_in[3];
  const float* curv   = (const float*)d_in[4];
  float* outp = (float*)d_out;

  float* ws = (float*)d_ws;
  unsigned short* v_tan_bf = (unsigned short*)ws;
  unsigned short* attn_bf  = (unsigned short*)ws;
  float* qkv   = ws + 1572864;
  float* v_out = qkv;
  unsigned short* qh  = (unsigned short*)(qkv + 9437184);
  unsigned short* kh  = qh + 3145728;
  unsigned short* vth = kh + 3145728;
  unsigned short* wqkv_bf  = vth + 3145728;
  unsigned short* wproj_bf = wqkv_bf + 1769472;
  float2* qn2 = (float2*)(wproj_bf + 589824);
  float2* kn2 = qn2 + 49152;

  conv_bf16_2<<<dim3((2359296 / 4 + 255) / 256), dim3(256), 0, stream>>>(
      w_qkv, 1769472, w_proj, 589824, wqkv_bf, wproj_bf);
  log0_kernel<<<dim3(ROWS / 4), dim3(256), 0, stream>>>(x, curv, v_tan_bf);
  gemm_nt_dbuf<128, 128><<<dim3(QKV_COLS / 128, ROWS / 128), dim3(256), 0, stream>>>(
      v_tan_bf, wqkv_bf, qkv, ROWS, QKV_COLS, DIM, nullptr);
  qkv_prep<<<dim3(SEQ / 64, NHEAD, 2), dim3(256), 0, stream>>>(qkv, curv, qh, kh, vth,
                                                               qn2, kn2);
  flash_mfma<<<dim3(768), dim3(256), 0, stream>>>(qh, kh, vth, qn2, kn2, attn_bf);
  gemm_nt_dbuf<64, 64><<<dim3(DIM / 64, ROWS / 64), dim3(256), 0, stream>>>(
      attn_bf, wproj_bf, v_out, ROWS, DIM, DIM, b_proj);
  exp0_out_kernel<<<dim3(ROWS / 4), dim3(256), 0, stream>>>(v_out, curv, outp);
}

// Round 10
// 205.709 us; speedup vs baseline: 1.2695x; 1.0832x over previous
//
#include <hip/hip_runtime.h>
#include <cmath>

#define ROWS 4096      // B*N
#define DIM 768        // D
#define QKV_COLS 2304  // 3*D
#define NHEAD 12
#define HEAD_DIM 64
#define SEQ 2048
#define PADK 72        // LDS row stride (bf16) for VALU-written tiles (Ps)

static constexpr float EPS_F = 1e-8f;

typedef __bf16 bfrag __attribute__((ext_vector_type(8)));   // 8 bf16 = 4 VGPR (MFMA A/B frag)
typedef float  f32x4 __attribute__((ext_vector_type(4)));   // MFMA C/D frag

__device__ __forceinline__ float wave_sum64(float v) {
#pragma unroll
  for (int off = 1; off < 64; off <<= 1) v += __shfl_xor(v, off, 64);
  return v;
}

__device__ __forceinline__ unsigned short f2bf(float f) {
  unsigned u = __float_as_uint(f);
  u += 0x7fffu + ((u >> 16) & 1u);
  return (unsigned short)(u >> 16);
}

// fast tanh(x)/x for x>0:  t=(e-1)/(e+1), e=2^(x*2*log2e);  ->1 as x->0
__device__ __forceinline__ float tanh_over_x(float x) {
  const float e  = __builtin_amdgcn_exp2f(x * 2.8853900817779268f);
  const float th = (e - 1.0f) * __builtin_amdgcn_rcpf(e + 1.0f);
  return (x < 1e-4f) ? 1.0f : th * __builtin_amdgcn_rcpf(x);
}

__device__ __forceinline__ void gl_lds16(const void* g, void* l) {
  __builtin_amdgcn_global_load_lds((const __attribute__((address_space(1))) void*)g,
                                   (__attribute__((address_space(3))) void*)l, 16, 0, 0);
}

// ------------- fused: log0 -> bf16 tangent vectors  +  weight f32->bf16 casts -------------
__global__ __launch_bounds__(256) void log0_conv(const float* __restrict__ x,
                                                 const float* __restrict__ cptr,
                                                 unsigned short* __restrict__ vout,
                                                 const float* __restrict__ wa, int na,
                                                 const float* __restrict__ wb, int nb,
                                                 unsigned short* __restrict__ da,
                                                 unsigned short* __restrict__ db) {
  if (blockIdx.x >= ROWS / 4) {
    const int i = ((blockIdx.x - ROWS / 4) * 256 + threadIdx.x) * 4;
    const float* s;
    unsigned short* d;
    int j;
    if (i < na) { s = wa; d = da; j = i; }
    else { j = i - na; if (j >= nb) return; s = wb; d = db; }
    const float4 v = *(const float4*)(s + j);
    ushort4 o;
    o.x = f2bf(v.x); o.y = f2bf(v.y); o.z = f2bf(v.z); o.w = f2bf(v.w);
    *(ushort4*)(d + j) = o;
    return;
  }
  const int lane = threadIdx.x & 63;
  const int row  = (blockIdx.x << 2) + (threadIdx.x >> 6);
  const float* xr = x + (size_t)row * DIM;
  unsigned short* vr = vout + (size_t)row * DIM;
  float vals[12];
  float ss = 0.f;
#pragma unroll
  for (int i = 0; i < 12; ++i) {
    float t = xr[lane + (i << 6)];
    vals[i] = t;
    ss += t * t;
  }
  ss = wave_sum64(ss);
  const float sc  = sqrtf(cptr[0]);
  const float n   = fmaxf(sqrtf(ss), EPS_F);
  const float scn = sc * n;
  const float t   = fminf(scn, 1.0f - 1e-7f);
  const float ath = 0.34657359027997264f *
                    __builtin_amdgcn_logf((1.0f + t) * __builtin_amdgcn_rcpf(1.0f - t));
  const float f   = (scn < 1e-4f) ? 1.0f : ath * __builtin_amdgcn_rcpf(scn);
#pragma unroll
  for (int i = 0; i < 12; ++i) vr[lane + (i << 6)] = f2bf(vals[i] * f);
}

// ---------------- final exp0: out = tanh(sc*n) * v / (sc*n) ----------------
__global__ __launch_bounds__(256) void exp0_out_kernel(const float* __restrict__ vin,
                                                       const float* __restrict__ cptr,
                                                       float* __restrict__ outp) {
  const int lane = threadIdx.x & 63;
  const int row  = (blockIdx.x << 2) + (threadIdx.x >> 6);
  const float* vr = vin + (size_t)row * DIM;
  float* orow = outp + (size_t)row * DIM;
  float vals[12];
  float ss = 0.f;
#pragma unroll
  for (int i = 0; i < 12; ++i) {
    float t = vr[lane + (i << 6)];
    vals[i] = t;
    ss += t * t;
  }
  ss = wave_sum64(ss);
  const float sc = sqrtf(cptr[0]);
  const float n  = fmaxf(sqrtf(ss), EPS_F);
  const float f  = tanh_over_x(sc * n);
#pragma unroll
  for (int i = 0; i < 12; ++i) orow[lane + (i << 6)] = vals[i] * f;
}

// ---------------- MFMA GEMM NT, prefetch double-buffered (proj GEMM) ----------------
template<int BM, int BN>
__global__ __launch_bounds__(256) void gemm_nt_dbuf(const unsigned short* __restrict__ A,
                                                    const unsigned short* __restrict__ B,
                                                    float* __restrict__ C,
                                                    int M, int Ncols, int K,
                                                    const float* __restrict__ bias) {
  constexpr int FI = BM / 32;
  constexpr int FJ = BN / 32;
  constexpr int CH = BM / 64;
  __shared__ unsigned short As[2][BM * 32];
  __shared__ unsigned short Bs[2][BN * 32];
  const int tid = threadIdx.x;
  const int w = tid >> 6, lane = tid & 63;
  const int lq = lane & 15, quad = lane >> 4;
  const int wr = w >> 1, wc = w & 1;
  const int row0 = blockIdx.y * BM;
  const int col0 = blockIdx.x * BN;
  const int srow  = lane >> 2;
  const int skoff = (lane & 3) << 3;

  f32x4 acc[FI][FJ];
#pragma unroll
  for (int i = 0; i < FI; ++i)
#pragma unroll
    for (int j = 0; j < FJ; ++j) acc[i][j] = (f32x4){0.f, 0.f, 0.f, 0.f};

  auto pf = [&](int k0, int buf) {
#pragma unroll
    for (int c = 0; c < CH; ++c) {
      const int r = c * 64 + w * 16;
      gl_lds16(A + (size_t)(row0 + r + srow) * K + k0 + skoff, &As[buf][r * 32]);
      gl_lds16(B + (size_t)(col0 + r + srow) * K + k0 + skoff, &Bs[buf][r * 32]);
    }
  };

  pf(0, 0);
  const int NIT = K / 32;
  for (int it = 0; it < NIT; ++it) {
    const int buf = it & 1;
    __syncthreads();
    if (it + 1 < NIT) pf((it + 1) * 32, buf ^ 1);

    bfrag af[FI], bfg[FJ];
#pragma unroll
    for (int i = 0; i < FI; ++i)
      af[i] = *(const bfrag*)&As[buf][(wr * (BM / 2) + i * 16 + lq) * 32 + (quad << 3)];
#pragma unroll
    for (int j = 0; j < FJ; ++j)
      bfg[j] = *(const bfrag*)&Bs[buf][(wc * (BN / 2) + j * 16 + lq) * 32 + (quad << 3)];
#pragma unroll
    for (int i = 0; i < FI; ++i)
#pragma unroll
      for (int j = 0; j < FJ; ++j)
        acc[i][j] = __builtin_amdgcn_mfma_f32_16x16x32_bf16(af[i], bfg[j], acc[i][j], 0, 0, 0);
  }

#pragma unroll
  for (int i = 0; i < FI; ++i) {
    const int crow = row0 + wr * (BM / 2) + i * 16 + (quad << 2);
#pragma unroll
    for (int j = 0; j < FJ; ++j) {
      const int col = col0 + wc * (BN / 2) + j * 16 + lq;
      const float bj = bias ? bias[col] : 0.0f;
      float* cp = C + (size_t)crow * Ncols + col;
#pragma unroll
      for (int r = 0; r < 4; ++r)
        cp[(size_t)r * Ncols] = acc[i][j][r] + bj;
    }
  }
}

// ------------- fused QKV GEMM: 128x128 m97-style + exp0/norm/V-transpose epilogue -------
// Each wave's acc = 64 tokens x one full 64-d head (col half == head, 768%128-aligned).
// q/k segments: ss = sum_j acc^2 + 4 xor-shuffles over lq-group -> f=tanh/x -> bf16 qh/kh
// + SoA norms (nrm, 1/(1-clamp)). v segment: transposed bf16 stores into vth[bh][d][seq].
__global__ __launch_bounds__(256) void gemm_qkv_fused(const unsigned short* __restrict__ A,
                                                      const unsigned short* __restrict__ B,
                                                      const float* __restrict__ cptr,
                                                      unsigned short* __restrict__ qh,
                                                      unsigned short* __restrict__ kh,
                                                      unsigned short* __restrict__ vth,
                                                      float* __restrict__ qnA,
                                                      float* __restrict__ qnB,
                                                      float* __restrict__ knA,
                                                      float* __restrict__ knB) {
  __shared__ unsigned short As[2][128 * 32];
  __shared__ unsigned short Bs[2][128 * 32];
  const int tid = threadIdx.x;
  const int w = tid >> 6, lane = tid & 63;
  const int lq = lane & 15, quad = lane >> 4;
  const int wr = w >> 1, wc = w & 1;
  const int row0 = blockIdx.y << 7;
  const int col0 = blockIdx.x << 7;
  const int srow  = lane >> 2;
  const int skoff = (lane & 3) << 3;

  f32x4 acc[4][4];
#pragma unroll
  for (int i = 0; i < 4; ++i)
#pragma unroll
    for (int j = 0; j < 4; ++j) acc[i][j] = (f32x4){0.f, 0.f, 0.f, 0.f};

  auto pf = [&](int k0, int buf) {
#pragma unroll
    for (int c = 0; c < 2; ++c) {
      const int r = c * 64 + w * 16;
      gl_lds16(A + (size_t)(row0 + r + srow) * DIM + k0 + skoff, &As[buf][r * 32]);
      gl_lds16(B + (size_t)(col0 + r + srow) * DIM + k0 + skoff, &Bs[buf][r * 32]);
    }
  };

  pf(0, 0);
  for (int it = 0; it < DIM / 32; ++it) {
    const int buf = it & 1;
    __syncthreads();
    if (it + 1 < DIM / 32) pf((it + 1) * 32, buf ^ 1);

    bfrag af[4], bfg[4];
#pragma unroll
    for (int i = 0; i < 4; ++i)
      af[i] = *(const bfrag*)&As[buf][((wr << 6) + (i << 4) + lq) * 32 + (quad << 3)];
#pragma unroll
    for (int j = 0; j < 4; ++j)
      bfg[j] = *(const bfrag*)&Bs[buf][((wc << 6) + (j << 4) + lq) * 32 + (quad << 3)];
#pragma unroll
    for (int i = 0; i < 4; ++i)
#pragma unroll
      for (int j = 0; j < 4; ++j)
        acc[i][j] = __builtin_amdgcn_mfma_f32_16x16x32_bf16(af[i], bfg[j], acc[i][j], 0, 0, 0);
  }

  // ---- fused epilogue ----
  const int colw = col0 + (wc << 6);          // wave's 64-col base = one head slice
  const int seg  = colw / DIM;                // 0=q, 1=k, 2=v
  const int hh   = (colw % DIM) >> 6;
  const int rowb = row0 + (wr << 6);

  if (seg == 2) {
#pragma unroll
    for (int i = 0; i < 4; ++i)
#pragma unroll
      for (int r = 0; r < 4; ++r) {
        const int rowg = rowb + (i << 4) + (quad << 2) + r;
        const int bh = (rowg >> 11) * NHEAD + hh;
        const int n_ = rowg & 2047;
#pragma unroll
        for (int j = 0; j < 4; ++j)
          vth[((size_t)bh * HEAD_DIM + (j << 4) + lq) * SEQ + n_] = f2bf(acc[i][j][r]);
      }
  } else {
    unsigned short* dst = seg ? kh : qh;
    float* nA = seg ? knA : qnA;
    float* nB = seg ? knB : qnB;
    const float sc = sqrtf(cptr[0]);
#pragma unroll
    for (int i = 0; i < 4; ++i)
#pragma unroll
      for (int r = 0; r < 4; ++r) {
        float ss = acc[i][0][r] * acc[i][0][r];
        ss = fmaf(acc[i][1][r], acc[i][1][r], ss);
        ss = fmaf(acc[i][2][r], acc[i][2][r], ss);
        ss = fmaf(acc[i][3][r], acc[i][3][r], ss);
        ss += __shfl_xor(ss, 1, 64);
        ss += __shfl_xor(ss, 2, 64);
        ss += __shfl_xor(ss, 4, 64);
        ss += __shfl_xor(ss, 8, 64);
        const float nn = fmaxf(sqrtf(ss), EPS_F);
        const float f  = tanh_over_x(sc * nn);
        const int rowg = rowb + (i << 4) + (quad << 2) + r;
        const int bh = (rowg >> 11) * NHEAD + hh;
        const int n_ = rowg & 2047;
        unsigned short* rp = dst + ((size_t)bh * SEQ + n_) * HEAD_DIM;
#pragma unroll
        for (int j = 0; j < 4; ++j)
          rp[(j << 4) + lq] = f2bf(acc[i][j][r] * f);
        if (lq == 0) {
          const float nrm = ss * f * f;
          nA[(size_t)bh * SEQ + n_] = nrm;
          nB[(size_t)bh * SEQ + n_] = 1.0f / (1.0f - fminf(nrm, 0.99f));
        }
      }
  }
}

// ------------- MFMA flash attention, S^T form, prefetch double-buffered -------------
// block = flat -> (bh = flat%24, qt = flat/24): 32 blocks per (b,h) share one XCD's L2.
// 4 waves x 16-query strips; 64-key rounds, one barrier each, K/V prefetched into the
// alternate LDS buffer; kn norms read direct from global (SoA, L2-hot) -> off the LDS pipe.
// l computed by MFMA vs a ones-fragment -> row-aligned with oacc.
__global__ __launch_bounds__(256) void flash_mfma(const unsigned short* __restrict__ qh,
                                                  const unsigned short* __restrict__ kh,
                                                  const unsigned short* __restrict__ vth,
                                                  const float* __restrict__ qnA,
                                                  const float* __restrict__ qnB,
                                                  const float* __restrict__ knA,
                                                  const float* __restrict__ knB,
                                                  unsigned short* __restrict__ attn_out) {
  const int flat = blockIdx.x;
  const int bhid = flat % 24;
  const int qt   = flat / 24;
  const int h = bhid % NHEAD, b = bhid / NHEAD;
  const int bh = b * NHEAD + h;
  const int tid = threadIdx.x;
  const int w = tid >> 6, lane = tid & 63;
  const int lq = lane & 15, quad = lane >> 4;

  __shared__ unsigned short Ks[2][64 * 64];  // swizzled [key][hd]
  __shared__ unsigned short Vt[2][64 * 64];  // swizzled [d][key]
  __shared__ unsigned short Ps[64 * PADK];   // [q][key], stride 72

  const unsigned short* qbase = qh + ((size_t)bh * SEQ + (size_t)qt * 64) * HEAD_DIM;
  const float* knAb = knA + (size_t)bh * SEQ;
  const float* knBb = knB + (size_t)bh * SEQ;

  const int srow = tid >> 3, spos = tid & 7;
  const int sB = spos ^ (srow & 7);
  const char* kgsrc = (const char*)(kh + (size_t)bh * SEQ * HEAD_DIM) + (size_t)srow * 128 + sB * 16;
  const char* vgsrc = (const char*)(vth + (size_t)bh * HEAD_DIM * SEQ) + (size_t)srow * 4096 + sB * 16;

  auto prefetch = [&](int kt, int buf) {
    const char* kp = kgsrc + (size_t)kt * 8192;  // 64 keys * 128B
    const char* vp = vgsrc + (size_t)kt * 128;   // 64 keys * 2B per d-row
    gl_lds16(kp,          (char*)Ks[buf] + w * 1024);
    gl_lds16(kp + 4096,   (char*)Ks[buf] + 4096 + w * 1024);
    gl_lds16(vp,          (char*)Vt[buf] + w * 1024);
    gl_lds16(vp + 131072, (char*)Vt[buf] + 4096 + w * 1024);
  };

  // Q fragments (B operand in S^T): frag[l][j] = Q[q = w*16+(l&15)][hd = khf*32+quad*8+j]
  bfrag aq[2];
#pragma unroll
  for (int khf = 0; khf < 2; ++khf)
    aq[khf] = *(const bfrag*)(qbase + (size_t)(w * 16 + lq) * HEAD_DIM + khf * 32 + quad * 8);

  const float qnS = qnA[(size_t)bh * SEQ + qt * 64 + w * 16 + lq];
  const float rqS = 2.0f * qnB[(size_t)bh * SEQ + qt * 64 + w * 16 + lq];

  bfrag ones;
#pragma unroll
  for (int j = 0; j < 8; ++j) ones[j] = (__bf16)1.0f;

  f32x4 oacc[4];
  f32x4 lacc = (f32x4){0.f, 0.f, 0.f, 0.f};
#pragma unroll
  for (int d = 0; d < 4; ++d) oacc[d] = (f32x4){0.f, 0.f, 0.f, 0.f};
  const int swz = lq & 7;

  prefetch(0, 0);
  for (int kt = 0; kt < SEQ / 64; ++kt) {
    const int buf = kt & 1;
    const int key0 = kt * 64;
    __syncthreads();  // drains prefetch(kt): tiles[buf] ready; all waves done with buf^1
    if (kt + 1 < SEQ / 64) prefetch(kt + 1, buf ^ 1);

    // kn norms direct from global (L2-hot): issued here, consumed after the MFMA block
    f32x4 kna[4], knr[4];
#pragma unroll
    for (int st = 0; st < 4; ++st) {
      kna[st] = *(const f32x4*)(knAb + key0 + st * 16 + (quad << 2));
      knr[st] = *(const f32x4*)(knBb + key0 + st * 16 + (quad << 2));
    }

    // ---- S^T strip [64k x 16q] = K·Q^T via MFMA ----
    f32x4 s[4];
#pragma unroll
    for (int st = 0; st < 4; ++st) s[st] = (f32x4){0.f, 0.f, 0.f, 0.f};
#pragma unroll
    for (int khf = 0; khf < 2; ++khf)
#pragma unroll
      for (int st = 0; st < 4; ++st) {
        const bfrag ak = *(const bfrag*)&Ks[buf][(st * 16 + lq) * 64 + (((khf << 2) + quad) ^ swz) * 8];
        s[st] = __builtin_amdgcn_mfma_f32_16x16x32_bf16(ak, aq[khf], s[st], 0, 0, 0);
      }

    // ---- w = (inner + sqrt(inner^2-1))^(-1/8); pack 4 keys via v_perm ----
#pragma unroll
    for (int st = 0; st < 4; ++st) {
      unsigned u[4];
#pragma unroll
      for (int i = 0; i < 4; ++i) {
        float tt = fmaf(-2.0f, s[st][i], qnS + kna[st][i]);
        tt = fmaxf(tt, 0.0f);
        const float inner = fmaf(tt, rqS * knr[st][i], 1.0f);
        const float root = __builtin_amdgcn_sqrtf(fmaf(inner, inner, -1.0f));
        const float wgt = __builtin_amdgcn_exp2f(-0.125f * __builtin_amdgcn_logf(inner + root));
        u[i] = __float_as_uint(wgt);
      }
      uint2 pk;
      pk.x = __builtin_amdgcn_perm(u[1], u[0], 0x07060302u);
      pk.y = __builtin_amdgcn_perm(u[3], u[2], 0x07060302u);
      *(uint2*)&Ps[(w * 16 + lq) * PADK + st * 16 + quad * 4] = pk;
    }

    // ---- O += P·V ; l += P·1 (intra-wave Ps, DS in-order: no barrier) ----
#pragma unroll
    for (int khf = 0; khf < 2; ++khf) {
      const bfrag ap = *(const bfrag*)&Ps[(w * 16 + lq) * PADK + khf * 32 + quad * 8];
      lacc = __builtin_amdgcn_mfma_f32_16x16x32_bf16(ap, ones, lacc, 0, 0, 0);
#pragma unroll
      for (int d = 0; d < 4; ++d) {
        const bfrag bv = *(const bfrag*)&Vt[buf][(d * 16 + lq) * 64 + (((khf << 2) + quad) ^ swz) * 8];
        oacc[d] = __builtin_amdgcn_mfma_f32_16x16x32_bf16(ap, bv, oacc[d], 0, 0, 0);
      }
    }
  }

  // lacc C-layout: row = q = quad*4+i (all cols equal) — aligned with oacc rows
  float rl4[4];
#pragma unroll
  for (int i = 0; i < 4; ++i) rl4[i] = __builtin_amdgcn_rcpf(lacc[i]);

  unsigned short* ob = attn_out + ((size_t)b * SEQ + (size_t)qt * 64 + w * 16) * DIM + h * HEAD_DIM;
#pragma unroll
  for (int d = 0; d < 4; ++d)
#pragma unroll
    for (int i = 0; i < 4; ++i)
      ob[(size_t)(quad * 4 + i) * DIM + d * 16 + lq] = f2bf(oacc[d][i] * rl4[i]);
}

extern "C" void kernel_launch(void* const* d_in, const int* in_sizes, int n_in,
                              void* d_out, int out_size, void* d_ws, size_t ws_size,
                              hipStream_t stream) {
  const float* x      = (const float*)d_in[0];
  const float* w_qkv  = (const float*)d_in[1];
  const float* w_proj = (const float*)d_in[2];
  const float* b_proj = (const float*)d_in[3];
  const float* curv   = (const float*)d_in[4];
  float* outp = (float*)d_out;

  float* ws = (float*)d_ws;
  // region A (bf16 3,145,728): v_tan_bf during QKV GEMM; attn_bf during proj GEMM
  unsigned short* v_tan_bf = (unsigned short*)ws;
  unsigned short* attn_bf  = (unsigned short*)ws;
  float* v_out = ws + 1572864;                         // 3,145,728 f
  unsigned short* qh  = (unsigned short*)(v_out + 3145728);
  unsigned short* kh  = qh + 3145728;
  unsigned short* vth = kh + 3145728;
  unsigned short* wqkv_bf  = vth + 3145728;            // 1,769,472 bf16
  unsigned short* wproj_bf = wqkv_bf + 1769472;        // 589,824 bf16
  float* qnA = (float*)(wproj_bf + 589824);            // 49,152 f each
  float* qnB = qnA + 49152;
  float* knA = qnB + 49152;
  float* knB = knA + 49152;

  log0_conv<<<dim3(ROWS / 4 + 2304), dim3(256), 0, stream>>>(
      x, curv, v_tan_bf, w_qkv, 1769472, w_proj, 589824, wqkv_bf, wproj_bf);
  gemm_qkv_fused<<<dim3(QKV_COLS / 128, ROWS / 128), dim3(256), 0, stream>>>(
      v_tan_bf, wqkv_bf, curv, qh, kh, vth, qnA, qnB, knA, knB);
  flash_mfma<<<dim3(768), dim3(256), 0, stream>>>(qh, kh, vth, qnA, qnB, knA, knB, attn_bf);
  gemm_nt_dbuf<64, 64><<<dim3(DIM / 64, ROWS / 64), dim3(256), 0, stream>>>(
      attn_bf, wproj_bf, v_out, ROWS, DIM, DIM, b_proj);
  exp0_out_kernel<<<dim3(ROWS / 4), dim3(256), 0, stream>>>(v_out, curv, outp);
}